// Round 2
// baseline (164.488 us; speedup 1.0000x reference)
//
#include <hip/hip_runtime.h>

// MatrixFactorization: out[n] = dot(concat(Wdow[dow],Wtim[tim],Wmon[mon],Wday[day]), Witem[dest])
//
// Evidence ladder (bench dur): R1 direct fp32 186 -> R5 bin32 fp32 168 -> R9 bin32 bf16 153
// -> R11 direct-out 151 -> R12 f16 dot2 + cl-hoist 147.5.
// R13: DELETE the Witem f16 conversion (77MB streaming in prep = ~12us, re-paid every iter
// because ws is re-poisoned). R9's fp32-gather loss was an NB=32 artifact: 4 buckets x
// 3125 rows x 512B = 6.4MB > 4MB XCD L2 -> thrash. With NB=64 + 8 XCD phases, the
// per-phase fp32 working set is 1563 rows x 512B = 0.8MB -> L2-resident, no conversion
// needed. prep shrinks to pure binning (20MB idx + 8MB payload). Main gathers fp32 direct.
//   - LDS tab rows padded to stride 36 floats (144B): stride 128B would put all 8
//     sample-groups of a wave on identical banks (8-way conflict = 2.94x on every
//     tab ds_read_b128); 36 rotates banks by 4/row -> ~conflict-free. 16B align kept.
//   - main __launch_bounds__(256,4): fp32 keeps 16 float4 fragments live (~116 VGPR);
//     a (256,8) 64-VGPR cap would spill.
//
// ws (~8.5 MB): [0,128K) clG int2[256*64] | [128K) payload u64 8MB.  small ws: fallback.

typedef unsigned long long u64;

constexpr int NDIM    = 32;
constexpr int RSTRIDE = 36;                 // padded LDS row stride (floats)
constexpr int B_DOW = 0;
constexpr int B_TIM = B_DOW + 7  * RSTRIDE; // 252
constexpr int B_MON = B_TIM + 24 * RSTRIDE; // 1116
constexpr int B_DAY = B_MON + 12 * RSTRIDE; // 1548
constexpr int TAB_TOT = B_DAY + 31 * RSTRIDE; // 2664 floats = 10656 B

constexpr int NB     = 64;       // dest buckets (dest / 1563)
constexpr int DDIV   = 1563;
constexpr int SLICES = 256;      // bin slices
constexpr int SPB    = 4096;     // samples per slice
constexpr int BIN_T  = 1024;
constexpr int IPT    = SPB / BIN_T;  // 4

__device__ __forceinline__ void load_tab(float* tab, const float* Wdow, const float* Wtim,
                                         const float* Wmon, const float* Wday, int nthr) {
    const int t = threadIdx.x;
    for (int i = t; i < 7  * NDIM; i += nthr) tab[B_DOW + (i >> 5) * RSTRIDE + (i & 31)] = Wdow[i];
    for (int i = t; i < 24 * NDIM; i += nthr) tab[B_TIM + (i >> 5) * RSTRIDE + (i & 31)] = Wtim[i];
    for (int i = t; i < 12 * NDIM; i += nthr) tab[B_MON + (i >> 5) * RSTRIDE + (i & 31)] = Wmon[i];
    for (int i = t; i < 31 * NDIM; i += nthr) tab[B_DAY + (i >> 5) * RSTRIDE + (i & 31)] = Wday[i];
}

// ---------- Pass 1: bin slice b into 64 dest-buckets (no conversion anymore) ----------
__global__ __launch_bounds__(BIN_T)
void prep_kernel(const int* __restrict__ dow, const int* __restrict__ tim,
                 const int* __restrict__ mon, const int* __restrict__ day,
                 const int* __restrict__ dest,
                 int2* __restrict__ clG,
                 u64* __restrict__ payload, int n)
{
    __shared__ u64 stage[SPB];              // 32 KB
    __shared__ int hist[NB], cursor[NB];

    const int t = threadIdx.x, b = blockIdx.x;
    const int g0 = b * SPB;
    const int rem = n - g0;
    const int len = rem < SPB ? rem : SPB;

    // (1) hoist bin index loads
    int dreg[IPT], pkreg[IPT];
#pragma unroll
    for (int i = 0; i < IPT; i++) {
        const int k = i * BIN_T + t;
        if (k < len) {
            const int idx = g0 + k;
            dreg[i]  = dest[idx];
            pkreg[i] = dow[idx] | (tim[idx] << 3) | (mon[idx] << 8) | (day[idx] << 12);
        } else { dreg[i] = -1; pkreg[i] = 0; }
    }

    // (2) histogram -> wave-parallel exclusive scan -> scatter to bucket-ordered stage
    if (t < NB) hist[t] = 0;
    __syncthreads();
#pragma unroll
    for (int i = 0; i < IPT; i++)
        if (dreg[i] >= 0) atomicAdd(&hist[dreg[i] / DDIV], 1);
    __syncthreads();
    if (t < 64) {                           // one full wave scans all 64 bins
        int v = hist[t];
#pragma unroll
        for (int d = 1; d < 64; d <<= 1) {
            const int nv = __shfl_up(v, d);
            if (t >= d) v += nv;
        }
        const int base = v - hist[t];
        cursor[t] = base;
        clG[b * NB + t] = make_int2(hist[t], base);
    }
    __syncthreads();
#pragma unroll
    for (int i = 0; i < IPT; i++) {
        const int k = i * BIN_T + t;
        if (k < len) {
            const int j = atomicAdd(&cursor[dreg[i] / DDIV], 1);   // LDS atomic only
            stage[j] = (u64)(unsigned)(g0 + k)
                     | ((u64)(unsigned)dreg[i]  << 20)
                     | ((u64)(unsigned)pkreg[i] << 37);
        }
    }
    __syncthreads();
#pragma unroll
    for (int i = 0; i < IPT; i++) {
        const int k = i * BIN_T + t;
        if (k < len) payload[g0 + k] = stage[k];   // coalesced
    }
}

// ---------- Pass 2: XCD-phased binned dot, fp32 items direct from Witem ----------
__global__ __launch_bounds__(256, 4)
void mf_main(const u64* __restrict__ payload,
             const float* __restrict__ Wdow, const float* __restrict__ Wtim,
             const float* __restrict__ Wmon, const float* __restrict__ Wday,
             const float* __restrict__ Witem,
             const int2* __restrict__ clG,
             float* __restrict__ out)
{
    __shared__ float tab[TAB_TOT];

    const int tid = threadIdx.x;
    const int x = blockIdx.x & 7;   // intended XCD
    const int s = blockIdx.x >> 3;  // slice 0..255

    // hoisted phase descriptors (block-uniform -> likely SGPR)
    int2 cl[8];
#pragma unroll
    for (int p = 0; p < 8; p++) cl[p] = clG[s * NB + x + 8 * p];

    load_tab(tab, Wdow, Wtim, Wmon, Wday, 256);
    __syncthreads();

    const int sub = tid & 63;
    const int wv  = tid >> 6;       // wave 0..3
    const int g   = sub >> 3;       // 8-lane group 0..7
    const int l8  = sub & 7;
    const int col = l8 * 4;
    const int tb[4] = {B_DOW, B_TIM, B_MON, B_DAY};
    const int sh[4] = {37, 40, 45, 49};
    const int mk[4] = {7, 31, 15, 31};

    for (int p = 0; p < 8; p++) {           // bucket q = x + 8p: all blocks on XCD x
        const int L  = cl[p].x;             // walk the same 0.8MB bucket per phase
        const int st = s * SPB + cl[p].y;
        for (int i = wv * 16; i < L; i += 64) {
            const int i0 = i + g, i1 = i + 8 + g;
            const bool v0 = i0 < L, v1 = i1 < L;
            const u64 p0 = v0 ? payload[st + i0] : 0ull;
            const u64 p1 = v1 ? payload[st + i1] : 0ull;
            const int d0 = (int)((p0 >> 20) & 0x1FFFFull);
            const int d1 = (int)((p1 >> 20) & 0x1FFFFull);
            const float* r0 = Witem + (long)d0 * 128 + col;
            const float* r1 = Witem + (long)d1 * 128 + col;
            float4 it0[4], it1[4], us0[4], us1[4];
#pragma unroll
            for (int j = 0; j < 4; j++) it0[j] = *reinterpret_cast<const float4*>(r0 + j * NDIM);
#pragma unroll
            for (int j = 0; j < 4; j++) it1[j] = *reinterpret_cast<const float4*>(r1 + j * NDIM);
#pragma unroll
            for (int j = 0; j < 4; j++) {
                const int idx = (int)((p0 >> sh[j]) & (u64)mk[j]);
                us0[j] = *reinterpret_cast<const float4*>(&tab[tb[j] + idx * RSTRIDE + col]);
            }
#pragma unroll
            for (int j = 0; j < 4; j++) {
                const int idx = (int)((p1 >> sh[j]) & (u64)mk[j]);
                us1[j] = *reinterpret_cast<const float4*>(&tab[tb[j] + idx * RSTRIDE + col]);
            }
            float a0 = 0.f, a1 = 0.f;
#pragma unroll
            for (int j = 0; j < 4; j++) {
                a0 += it0[j].x * us0[j].x + it0[j].y * us0[j].y
                    + it0[j].z * us0[j].z + it0[j].w * us0[j].w;
                a1 += it1[j].x * us1[j].x + it1[j].y * us1[j].y
                    + it1[j].z * us1[j].z + it1[j].w * us1[j].w;
            }
            a0 += __shfl_xor(a0, 1);  a1 += __shfl_xor(a1, 1);
            a0 += __shfl_xor(a0, 2);  a1 += __shfl_xor(a1, 2);
            a0 += __shfl_xor(a0, 4);  a1 += __shfl_xor(a1, 4);
            if (l8 == 0) {  // direct out write; ids are slice-local -> one 16KB window/block
                if (v0) out[(int)(p0 & 0xFFFFFull)] = a0;
                if (v1) out[(int)(p1 & 0xFFFFFull)] = a1;
            }
        }
    }
}

// ---------- Fallback: direct fp32 ----------
__global__ __launch_bounds__(256, 8)
void mf_dot_kernel(const int* __restrict__ dow, const int* __restrict__ tim,
                   const int* __restrict__ mon, const int* __restrict__ day,
                   const int* __restrict__ dest,
                   const float* __restrict__ Wdow, const float* __restrict__ Wtim,
                   const float* __restrict__ Wmon, const float* __restrict__ Wday,
                   const float* __restrict__ Witem,
                   float* __restrict__ out, int n_samples)
{
    __shared__ float tab[TAB_TOT];
    load_tab(tab, Wdow, Wtim, Wmon, Wday, 256);
    __syncthreads();
    const int tid = threadIdx.x;
    const int lane = tid & 63, sub = lane & 31, wave = tid >> 6, half = lane >> 5;
    const int t = sub >> 3, dofs = (sub & 7) * 4;
    const int* idxp  = (t == 0) ? dow   : (t == 1) ? tim   : (t == 2) ? mon   : day;
    const int  tbase = (t == 0) ? B_DOW : (t == 1) ? B_TIM : (t == 2) ? B_MON : B_DAY;
    long n = (long)blockIdx.x * 8 + wave * 2 + half;
    const long stride = (long)gridDim.x * 8;
    for (; n < n_samples; n += stride) {
        const int idx = idxp[n];
        const int ds  = dest[n];
        const float4 u  = *reinterpret_cast<const float4*>(&tab[tbase + idx * RSTRIDE + dofs]);
        const float4 it = *reinterpret_cast<const float4*>(&Witem[(long)ds * 128 + sub * 4]);
        float r = u.x * it.x + u.y * it.y + u.z * it.z + u.w * it.w;
        r += __shfl_xor(r, 16); r += __shfl_xor(r, 8); r += __shfl_xor(r, 4);
        r += __shfl_xor(r, 2);  r += __shfl_xor(r, 1);
        if (sub == 0) out[n] = r;
    }
}

extern "C" void kernel_launch(void* const* d_in, const int* in_sizes, int n_in,
                              void* d_out, int out_size, void* d_ws, size_t ws_size,
                              hipStream_t stream)
{
    const int*   dow   = (const int*)d_in[0];
    const int*   tim   = (const int*)d_in[1];
    const int*   mon   = (const int*)d_in[2];
    const int*   day   = (const int*)d_in[3];
    const int*   dest  = (const int*)d_in[4];
    const float* Wdow  = (const float*)d_in[5];
    const float* Wtim  = (const float*)d_in[6];
    const float* Wmon  = (const float*)d_in[7];
    const float* Wday  = (const float*)d_in[8];
    const float* Witem = (const float*)d_in[9];
    float* out = (float*)d_out;

    const int n   = in_sizes[0];     // 1048576
    const int cap = SLICES * SPB;    // 1<<20

    const size_t off_pay = 128 * 1024;                   // clG int2[256*64] = 128KB exactly
    const size_t need    = off_pay + (size_t)cap * 8;    // ~8.5 MB

    if ((size_t)ws_size < need || n > cap) {
        hipLaunchKernelGGL(mf_dot_kernel, dim3(2048), dim3(256), 0, stream,
                           dow, tim, mon, day, dest,
                           Wdow, Wtim, Wmon, Wday, Witem, out, n);
        return;
    }

    int2* clG    = (int2*)d_ws;
    u64* payload = (u64*)((char*)d_ws + off_pay);

    hipLaunchKernelGGL(prep_kernel, dim3(SLICES), dim3(BIN_T), 0, stream,
                       dow, tim, mon, day, dest, clG, payload, n);
    hipLaunchKernelGGL(mf_main, dim3(SLICES * 8), dim3(256), 0, stream,
                       payload, Wdow, Wtim, Wmon, Wday, Witem, clG, out);
}

// Round 4
// 150.344 us; speedup vs baseline: 1.0941x; 1.0941x over previous
//
#include <hip/hip_runtime.h>

// MatrixFactorization: out[n] = dot(concat(Wdow[dow],Wtim[tim],Wmon[mon],Wday[day]), Witem[dest])
//
// Evidence ladder (bench dur): R1 direct fp32 186 -> R5 bin32 fp32 168 -> R9 bin32 bf16 153
// -> R11 direct-out 151 -> R12 f16 dot2 + cl-hoist 147.5 -> R13 fp32-direct NB=64 164.5 FAILED
// -> R14 (this kernel) not yet measured: round 3 was a GPUAcquisitionTimeout (infra), resubmit.
// R13 post-mortem (counters): VGPR_Count=32 (compiler serialized the 16-float4 fragment
// loads -> no MLP, latency exposed), FETCH 101MB vs 51 ideal (8-phase drift -> L2 thrash),
// WRITE 36MB vs 4 (out dirty-line eviction). fp32 direct gather is dead; f16 conversion
// stays (halves the dominant 512MB L2 gather stream).
// R14: keep conversion, DELETE the payload global round-trip + 2nd gather dispatch.
// Binning is block-local: bin_gather bins its slice into a bucket-SORTED LDS stage and
// gathers straight from it. Only the Witem f16 conversion crosses blocks -> it gets its
// own tiny streaming kernel. Sorted-linear walk replaces XCD phasing (all concurrent
// blocks traverse buckets in the same order; NB=64 -> 0.4MB/bucket working set).
//   - bin_gather: 512 blocks x 1024 thr, __launch_bounds__(1024,8): 2 blocks/CU = 100%
//     occupancy in gather phase, VGPR cap 64 (R12's f16 body fit this budget).
//   - LDS/block ~21KB: stage u64[2048] 16KB + tabh f16x2 4.7KB + hist/cursor.
//
// ws (25.6 MB): [0, we*2) Wh f16.  small ws or n>1M: direct fp32 fallback.

typedef unsigned long long u64;
typedef unsigned int uint;
typedef _Float16 half_t;
typedef half_t h2 __attribute__((ext_vector_type(2)));

#if __has_builtin(__builtin_amdgcn_fdot2)
#define HAVE_FDOT2 1
#else
#define HAVE_FDOT2 0
#endif

constexpr int NDIM = 32;
constexpr int SZ_DOW = 7 * NDIM, SZ_TIM = 24 * NDIM, SZ_MON = 12 * NDIM, SZ_DAY = 31 * NDIM;
constexpr int B_DOW = 0;
constexpr int B_TIM = B_DOW + SZ_DOW;   // 224
constexpr int B_MON = B_TIM + SZ_TIM;   // 992
constexpr int B_DAY = B_MON + SZ_MON;   // 1376
constexpr int TAB_TOT = B_DAY + SZ_DAY; // 2368 floats

constexpr int NB   = 64;        // dest buckets (dest / 1563), 0.4MB f16 rows per bucket
constexpr int DDIV = 1563;
constexpr int THR  = 1024;      // bin_gather block size (16 waves)
constexpr int SPB  = 2048;      // samples per slice/block
constexpr int IPT  = SPB / THR; // 2

__device__ __forceinline__ unsigned short f2h(float f) {   // RNE fp32->fp16
    return __builtin_bit_cast(unsigned short, (half_t)f);
}

__device__ __forceinline__ uint pack2h(float a, float b) {
    return (uint)f2h(a) | ((uint)f2h(b) << 16);
}

__device__ __forceinline__ float dp2(uint a, uint b, float c) {
#if HAVE_FDOT2
    return __builtin_amdgcn_fdot2(__builtin_bit_cast(h2, a), __builtin_bit_cast(h2, b), c, false);
#else
    const h2 x = __builtin_bit_cast(h2, a), y = __builtin_bit_cast(h2, b);
    return c + (float)x.x * (float)y.x + (float)x.y * (float)y.y;
#endif
}

// 16 dims: items (a,b) vs tab (ua,ub), two chains for ILP
__device__ __forceinline__ float dot16h(uint4 a, uint4 b, uint4 ua, uint4 ub) {
    float s0 = dp2(a.x, ua.x, 0.f);
    float s1 = dp2(a.y, ua.y, 0.f);
    s0 = dp2(a.z, ua.z, s0);
    s1 = dp2(a.w, ua.w, s1);
    s0 = dp2(b.x, ub.x, s0);
    s1 = dp2(b.y, ub.y, s1);
    s0 = dp2(b.z, ub.z, s0);
    s1 = dp2(b.w, ub.w, s1);
    return s0 + s1;
}

__device__ __forceinline__ void load_tab(float* tab, const float* Wdow, const float* Wtim,
                                         const float* Wmon, const float* Wday, int nthr) {
    const int t = threadIdx.x;
    for (int i = t; i < SZ_DOW; i += nthr) tab[B_DOW + i] = Wdow[i];
    for (int i = t; i < SZ_TIM; i += nthr) tab[B_TIM + i] = Wtim[i];
    for (int i = t; i < SZ_MON; i += nthr) tab[B_MON + i] = Wmon[i];
    for (int i = t; i < SZ_DAY; i += nthr) tab[B_DAY + i] = Wday[i];
}

// pack one table's fp32 rows into f16x2 pairs in LDS
__device__ __forceinline__ void load_tabh(uint* th, const float* W, int base, int sz,
                                          int t, int nthr) {
    const float2* src = (const float2*)W;
    for (int i = t; i < (sz >> 1); i += nthr) {
        const float2 v = src[i];
        th[(base >> 1) + i] = pack2h(v.x, v.y);
    }
}

// ---------- Pass 1: stream Witem fp32 -> f16 (only cross-block dependency) ----------
__global__ __launch_bounds__(256)
void convert_kernel(const float* __restrict__ Witem, unsigned short* __restrict__ Wh, int nf4)
{
    const float4* src = (const float4*)Witem;
    ushort4* dst = (ushort4*)Wh;
    const int stride = gridDim.x * 256;
    for (int i = blockIdx.x * 256 + threadIdx.x; i < nf4; i += stride) {
        const float4 v = src[i];
        ushort4 o;
        o.x = f2h(v.x); o.y = f2h(v.y); o.z = f2h(v.z); o.w = f2h(v.w);
        dst[i] = o;
    }
}

// ---------- Pass 2: bin slice into bucket-sorted LDS stage, gather straight from it ----------
__global__ __launch_bounds__(THR, 8)
void bin_gather(const int* __restrict__ dow, const int* __restrict__ tim,
                const int* __restrict__ mon, const int* __restrict__ day,
                const int* __restrict__ dest,
                const float* __restrict__ Wdow, const float* __restrict__ Wtim,
                const float* __restrict__ Wmon, const float* __restrict__ Wday,
                const unsigned short* __restrict__ Wh,
                float* __restrict__ out, int n)
{
    __shared__ u64 stage[SPB];              // 16 KB, bucket-sorted payload
    __shared__ uint tabh[TAB_TOT / 2];      // 4736 B
    __shared__ int hist[NB], cursor[NB];

    const int t = threadIdx.x, b = blockIdx.x;
    const int g0 = b * SPB;
    const int rem = n - g0;
    const int len = rem < SPB ? rem : SPB;

    // (1) hoist index loads (long-latency, issued first)
    int dreg[IPT], pkreg[IPT];
#pragma unroll
    for (int i = 0; i < IPT; i++) {
        const int k = i * THR + t;
        if (k < len) {
            const int idx = g0 + k;
            dreg[i]  = dest[idx];
            pkreg[i] = dow[idx] | (tim[idx] << 3) | (mon[idx] << 8) | (day[idx] << 12);
        } else { dreg[i] = -1; pkreg[i] = 0; }
    }

    // (2) user tables -> f16x2 LDS (overlaps idx-load latency)
    load_tabh(tabh, Wdow, B_DOW, SZ_DOW, t, THR);
    load_tabh(tabh, Wtim, B_TIM, SZ_TIM, t, THR);
    load_tabh(tabh, Wmon, B_MON, SZ_MON, t, THR);
    load_tabh(tabh, Wday, B_DAY, SZ_DAY, t, THR);

    // (3) histogram -> full-wave exclusive scan (NB=64) -> scatter bucket-sorted
    if (t < NB) hist[t] = 0;
    __syncthreads();
#pragma unroll
    for (int i = 0; i < IPT; i++)
        if (dreg[i] >= 0) atomicAdd(&hist[dreg[i] / DDIV], 1);
    __syncthreads();
    if (t < 64) {                           // one wave scans all 64 bins
        int v = hist[t];
#pragma unroll
        for (int d = 1; d < 64; d <<= 1) {
            const int nv = __shfl_up(v, d);
            if (t >= d) v += nv;
        }
        cursor[t] = v - hist[t];
    }
    __syncthreads();
#pragma unroll
    for (int i = 0; i < IPT; i++) {
        const int k = i * THR + t;
        if (k < len) {
            const int j = atomicAdd(&cursor[dreg[i] / DDIV], 1);   // LDS atomic only
            stage[j] = (u64)(unsigned)(g0 + k)
                     | ((u64)(unsigned)dreg[i]  << 20)
                     | ((u64)(unsigned)pkreg[i] << 37);
        }
    }
    __syncthreads();

    // (4) gather: 16 waves walk the sorted list linearly (bucket-ordered -> L2-local)
    const int sub = t & 63;
    const int wv  = t >> 6;            // wave 0..15
    const int g   = sub >> 3;          // 8-lane group 0..7
    const int l8  = sub & 7;
    const int jt   = l8 >> 1;          // table id
    const int half = (l8 & 1) * 16;    // 16-dim half within table
    const int tbj  = (jt == 0) ? B_DOW : (jt == 1) ? B_TIM : (jt == 2) ? B_MON : B_DAY;
    const int shj  = (jt == 0) ? 37    : (jt == 1) ? 40    : (jt == 2) ? 45    : 49;
    const int mkj  = (jt == 0) ? 7     : (jt == 1) ? 31    : (jt == 2) ? 15    : 31;
    const int tub  = (tbj + half) >> 1;  // uint base into tabh (16B-aligned)

    for (int i = wv * 16; i < len; i += 16 * (THR / 64)) {   // stride 256
        const int i0 = i + g, i1 = i + 8 + g;
        const bool v0 = i0 < len, v1 = i1 < len;
        const u64 c0 = v0 ? stage[i0] : 0ull;     // ds_read, 8-lane broadcast
        const u64 c1 = v1 ? stage[i1] : 0ull;

        const int d0 = (int)((c0 >> 20) & 0x1FFFFull);
        const int d1 = (int)((c1 >> 20) & 0x1FFFFull);

        const uint4* r0 = (const uint4*)(Wh + (long)d0 * 128 + (l8 << 4));
        const uint4* r1 = (const uint4*)(Wh + (long)d1 * 128 + (l8 << 4));
        const uint4 A0 = r0[0], B0 = r0[1];
        const uint4 A1 = r1[0], B1 = r1[1];

        const int ix0 = (int)((c0 >> shj) & (u64)mkj);
        const int ix1 = (int)((c1 >> shj) & (u64)mkj);
        const uint4* t0 = (const uint4*)&tabh[tub + ix0 * (NDIM / 2)];
        const uint4* t1 = (const uint4*)&tabh[tub + ix1 * (NDIM / 2)];
        const uint4 U00 = t0[0], U01 = t0[1];
        const uint4 U10 = t1[0], U11 = t1[1];

        float a0 = dot16h(A0, B0, U00, U01);
        float a1 = dot16h(A1, B1, U10, U11);

        a0 += __shfl_xor(a0, 1);  a1 += __shfl_xor(a1, 1);
        a0 += __shfl_xor(a0, 2);  a1 += __shfl_xor(a1, 2);
        a0 += __shfl_xor(a0, 4);  a1 += __shfl_xor(a1, 4);

        if (l8 == 0) {  // ids slice-local -> one 8KB out window per block
            if (v0) out[(int)(c0 & 0xFFFFFull)] = a0;
            if (v1) out[(int)(c1 & 0xFFFFFull)] = a1;
        }
    }
}

// ---------- Fallback: direct fp32 ----------
__global__ __launch_bounds__(256, 8)
void mf_dot_kernel(const int* __restrict__ dow, const int* __restrict__ tim,
                   const int* __restrict__ mon, const int* __restrict__ day,
                   const int* __restrict__ dest,
                   const float* __restrict__ Wdow, const float* __restrict__ Wtim,
                   const float* __restrict__ Wmon, const float* __restrict__ Wday,
                   const float* __restrict__ Witem,
                   float* __restrict__ out, int n_samples)
{
    __shared__ float tab[TAB_TOT];
    load_tab(tab, Wdow, Wtim, Wmon, Wday, 256);
    __syncthreads();
    const int tid = threadIdx.x;
    const int lane = tid & 63, sub = lane & 31, wave = tid >> 6, half = lane >> 5;
    const int t = sub >> 3, dofs = (sub & 7) * 4;
    const int* idxp  = (t == 0) ? dow   : (t == 1) ? tim   : (t == 2) ? mon   : day;
    const int  tbase = (t == 0) ? B_DOW : (t == 1) ? B_TIM : (t == 2) ? B_MON : B_DAY;
    long n = (long)blockIdx.x * 8 + wave * 2 + half;
    const long stride = (long)gridDim.x * 8;
    for (; n < n_samples; n += stride) {
        const int idx = idxp[n];
        const int ds  = dest[n];
        const float4 u  = *reinterpret_cast<const float4*>(&tab[tbase + idx * NDIM + dofs]);
        const float4 it = *reinterpret_cast<const float4*>(&Witem[(long)ds * 128 + sub * 4]);
        float r = u.x * it.x + u.y * it.y + u.z * it.z + u.w * it.w;
        r += __shfl_xor(r, 16); r += __shfl_xor(r, 8); r += __shfl_xor(r, 4);
        r += __shfl_xor(r, 2);  r += __shfl_xor(r, 1);
        if (sub == 0) out[n] = r;
    }
}

extern "C" void kernel_launch(void* const* d_in, const int* in_sizes, int n_in,
                              void* d_out, int out_size, void* d_ws, size_t ws_size,
                              hipStream_t stream)
{
    const int*   dow   = (const int*)d_in[0];
    const int*   tim   = (const int*)d_in[1];
    const int*   mon   = (const int*)d_in[2];
    const int*   day   = (const int*)d_in[3];
    const int*   dest  = (const int*)d_in[4];
    const float* Wdow  = (const float*)d_in[5];
    const float* Wtim  = (const float*)d_in[6];
    const float* Wmon  = (const float*)d_in[7];
    const float* Wday  = (const float*)d_in[8];
    const float* Witem = (const float*)d_in[9];
    float* out = (float*)d_out;

    const int n   = in_sizes[0];     // 1048576
    const int we  = in_sizes[9];     // 12,800,000
    const int cap = 1 << 20;         // payload id field = 20 bits

    const size_t need = (size_t)we * 2;   // Wh f16, 25.6 MB

    if ((size_t)ws_size < need || n > cap) {
        hipLaunchKernelGGL(mf_dot_kernel, dim3(2048), dim3(256), 0, stream,
                           dow, tim, mon, day, dest,
                           Wdow, Wtim, Wmon, Wday, Witem, out, n);
        return;
    }

    unsigned short* Wh = (unsigned short*)d_ws;
    const int blocks = (n + SPB - 1) / SPB;   // 512 at n=1M

    hipLaunchKernelGGL(convert_kernel, dim3(2048), dim3(256), 0, stream,
                       Witem, Wh, we >> 2);
    hipLaunchKernelGGL(bin_gather, dim3(blocks), dim3(THR), 0, stream,
                       dow, tim, mon, day, dest,
                       Wdow, Wtim, Wmon, Wday, Wh, out, n);
}

// Round 5
// 147.838 us; speedup vs baseline: 1.1126x; 1.0170x over previous
//
#include <hip/hip_runtime.h>

// MatrixFactorization: out[n] = dot(concat(Wdow[dow],Wtim[tim],Wmon[mon],Wday[day]), Witem[dest])
//
// Evidence ladder (bench dur): R1 direct 186 -> R5 bin32 fp32 168 -> R9 bin32 bf16 153
// -> R11 direct-out 151 -> R12 f16 dot2 + cl-hoist 147.5 -> R13 fp32 NB=64 164.5 FAILED
// -> R14 block-local bin (no phasing) 150.3 FAILED.
// R14 post-mortem: bin_gather 41.6us, VGPR=28 (compiler serialized gather chains, 2-way
// MLP, VALUBusy 16%), FETCH 109MB vs 46 ideal (no cross-block bucket concentration ->
// 2.5x L2 over-fetch). Lessons: (a) R12's XCD-phased bucket structure is right — the
// 16MB payload round-trip buys L2 residency; (b) every failure shares one proximate
// cause: compiler register-minimization serializes the gather loads.
// R15 = R12 + two changes to its main kernel:
//   1. phase->wave: wave w owns bucket x+8w entirely (same 3.2MB/XCD L2 footprint, but
//      one long 8-iter loop per wave instead of 4 pipeline restarts of 2 iters).
//   2. explicit 2-stage pipeline: payloads prefetched 2 iters ahead, item rows 1 ahead,
//      all next-iter loads issued BEFORE current-iter consume -> compiler emits
//      vmcnt(6)-style partial waits, 4 chains in flight. VGPR ~70-80 -> (256,6) cap 85
//      ((256,8)'s 64-cap is what forced serialization).
// Verification signal: mf_main_f16 VGPR_Count 60-85 = pipeline held; <=40 = defeated.
//
// ws full (~33.8 MB): [0,64K) clG int2 | [64K) Wh f16 25.6MB | payload u64 8MB
// mid (>=8.07MB): fp32-item path.  small: direct fallback.

typedef unsigned long long u64;
typedef unsigned int uint;
typedef _Float16 half_t;
typedef half_t h2 __attribute__((ext_vector_type(2)));

#if __has_builtin(__builtin_amdgcn_fdot2)
#define HAVE_FDOT2 1
#else
#define HAVE_FDOT2 0
#endif

constexpr int NDIM = 32;
constexpr int SZ_DOW = 7 * NDIM, SZ_TIM = 24 * NDIM, SZ_MON = 12 * NDIM, SZ_DAY = 31 * NDIM;
constexpr int B_DOW = 0;
constexpr int B_TIM = B_DOW + SZ_DOW;   // 224
constexpr int B_MON = B_TIM + SZ_TIM;   // 992
constexpr int B_DAY = B_MON + SZ_MON;   // 1376
constexpr int TAB_TOT = B_DAY + SZ_DAY; // 2368 floats

constexpr int NB     = 32;       // dest buckets (dest / 3125), 0.8MB f16 rows per bucket
constexpr int DDIV   = 3125;
constexpr int SLICES = 256;      // bin slices
constexpr int SPB    = 4096;     // samples per slice
constexpr int BIN_T  = 1024;
constexpr int IPT    = SPB / BIN_T;  // 4

__device__ __forceinline__ unsigned short f2h(float f) {   // RNE fp32->fp16
    return __builtin_bit_cast(unsigned short, (half_t)f);
}

__device__ __forceinline__ uint pack2h(float a, float b) {
    return (uint)f2h(a) | ((uint)f2h(b) << 16);
}

__device__ __forceinline__ float dp2(uint a, uint b, float c) {
#if HAVE_FDOT2
    return __builtin_amdgcn_fdot2(__builtin_bit_cast(h2, a), __builtin_bit_cast(h2, b), c, false);
#else
    const h2 x = __builtin_bit_cast(h2, a), y = __builtin_bit_cast(h2, b);
    return c + (float)x.x * (float)y.x + (float)x.y * (float)y.y;
#endif
}

// 16 dims: items (a,b) vs tab (ua,ub), two chains for ILP
__device__ __forceinline__ float dot16h(uint4 a, uint4 b, uint4 ua, uint4 ub) {
    float s0 = dp2(a.x, ua.x, 0.f);
    float s1 = dp2(a.y, ua.y, 0.f);
    s0 = dp2(a.z, ua.z, s0);
    s1 = dp2(a.w, ua.w, s1);
    s0 = dp2(b.x, ub.x, s0);
    s1 = dp2(b.y, ub.y, s1);
    s0 = dp2(b.z, ub.z, s0);
    s1 = dp2(b.w, ub.w, s1);
    return s0 + s1;
}

__device__ __forceinline__ void load_tab(float* tab, const float* Wdow, const float* Wtim,
                                         const float* Wmon, const float* Wday, int nthr) {
    const int t = threadIdx.x;
    for (int i = t; i < SZ_DOW; i += nthr) tab[B_DOW + i] = Wdow[i];
    for (int i = t; i < SZ_TIM; i += nthr) tab[B_TIM + i] = Wtim[i];
    for (int i = t; i < SZ_MON; i += nthr) tab[B_MON + i] = Wmon[i];
    for (int i = t; i < SZ_DAY; i += nthr) tab[B_DAY + i] = Wday[i];
}

// pack one table's fp32 rows into f16x2 pairs in LDS
__device__ __forceinline__ void load_tabh(uint* th, const float* W, int base, int sz,
                                          int t, int nthr) {
    const float2* src = (const float2*)W;
    for (int i = t; i < (sz >> 1); i += nthr) {
        const float2 v = src[i];
        th[(base >> 1) + i] = pack2h(v.x, v.y);
    }
}

// ---------- Pass 1: bin slice b + convert chunk b of Witem fp32->f16 ----------
__global__ __launch_bounds__(BIN_T)
void prep_kernel(const int* __restrict__ dow, const int* __restrict__ tim,
                 const int* __restrict__ mon, const int* __restrict__ day,
                 const int* __restrict__ dest,
                 int2* __restrict__ clG,
                 u64* __restrict__ payload, int n,
                 const float* __restrict__ Witem, unsigned short* __restrict__ Wh,
                 int witem_elems)
{
    __shared__ u64 stage[SPB];              // 32 KB
    __shared__ int hist[NB], cursor[NB];

    const int t = threadIdx.x, b = blockIdx.x;
    const int g0 = b * SPB;
    const int rem = n - g0;
    const int len = rem < SPB ? rem : SPB;

    // (1) hoist bin index loads
    int dreg[IPT], pkreg[IPT];
#pragma unroll
    for (int i = 0; i < IPT; i++) {
        const int k = i * BIN_T + t;
        if (k < len) {
            const int idx = g0 + k;
            dreg[i]  = dest[idx];
            pkreg[i] = dow[idx] | (tim[idx] << 3) | (mon[idx] << 8) | (day[idx] << 12);
        } else { dreg[i] = -1; pkreg[i] = 0; }
    }

    // (2) convert this block's contiguous chunk of Witem fp32 -> f16
    if (Wh) {
        const int nf4   = witem_elems >> 2;                 // 3.2M float4
        const int chunk = (nf4 + SLICES - 1) / SLICES;      // 12500
        const int c0    = b * chunk;
        const int c1    = min(c0 + chunk, nf4);
        const float4* src = (const float4*)Witem;
        ushort4* dst = (ushort4*)Wh;
        for (int i = c0 + t; i < c1; i += BIN_T) {
            const float4 v = src[i];
            ushort4 o;
            o.x = f2h(v.x); o.y = f2h(v.y); o.z = f2h(v.z); o.w = f2h(v.w);
            dst[i] = o;
        }
    }

    // (3) bin LDS phases
    if (t < NB) hist[t] = 0;
    __syncthreads();
#pragma unroll
    for (int i = 0; i < IPT; i++)
        if (dreg[i] >= 0) atomicAdd(&hist[dreg[i] / DDIV], 1);
    __syncthreads();
    if (t < 64) {                           // wave-parallel exclusive scan over 32 bins
        int v = (t < NB) ? hist[t] : 0;
#pragma unroll
        for (int d = 1; d < NB; d <<= 1) {
            const int nv = __shfl_up(v, d);
            if (t >= d) v += nv;
        }
        if (t < NB) {
            const int base = v - hist[t];
            cursor[t] = base;
            clG[b * NB + t] = make_int2(hist[t], base);
        }
    }
    __syncthreads();
#pragma unroll
    for (int i = 0; i < IPT; i++) {
        const int k = i * BIN_T + t;
        if (k < len) {
            const int j = atomicAdd(&cursor[dreg[i] / DDIV], 1);   // LDS atomic only
            stage[j] = (u64)(unsigned)(g0 + k)
                     | ((u64)(unsigned)dreg[i]  << 20)
                     | ((u64)(unsigned)pkreg[i] << 37);
        }
    }
    __syncthreads();
#pragma unroll
    for (int i = 0; i < IPT; i++) {
        const int k = i * BIN_T + t;
        if (k < len) payload[g0 + k] = stage[k];   // coalesced
    }
}

// ---------- Pass 2 (full): per-wave bucket, 2-stage pipelined f16 gather ----------
__global__ __launch_bounds__(256, 6)
void mf_main_f16(const u64* __restrict__ payload,
                 const float* __restrict__ Wdow, const float* __restrict__ Wtim,
                 const float* __restrict__ Wmon, const float* __restrict__ Wday,
                 const unsigned short* __restrict__ Wh,
                 const int2* __restrict__ clG,
                 float* __restrict__ out)
{
    __shared__ uint tabh[TAB_TOT / 2];      // f16x2-packed user tables (4736 B)

    const int tid = threadIdx.x;
    const int x = blockIdx.x & 7;   // intended XCD
    const int s = blockIdx.x >> 3;  // slice 0..255
    const int wv = tid >> 6;        // wave 0..3 -> owns bucket x + 8*wv

    const int2 cl = clG[s * NB + x + 8 * wv];   // wave-uniform

    load_tabh(tabh, Wdow, B_DOW, SZ_DOW, tid, 256);
    load_tabh(tabh, Wtim, B_TIM, SZ_TIM, tid, 256);
    load_tabh(tabh, Wmon, B_MON, SZ_MON, tid, 256);
    load_tabh(tabh, Wday, B_DAY, SZ_DAY, tid, 256);
    __syncthreads();

    const int sub = tid & 63;
    const int g   = sub >> 3;       // 8-lane group 0..7
    const int l8  = sub & 7;
    const int jt   = l8 >> 1;           // table id
    const int half = (l8 & 1) * 16;     // 16-dim half within table
    const int tbj  = (jt == 0) ? B_DOW : (jt == 1) ? B_TIM : (jt == 2) ? B_MON : B_DAY;
    const int shj  = (jt == 0) ? 37    : (jt == 1) ? 40    : (jt == 2) ? 45    : 49;
    const int mkj  = (jt == 0) ? 7     : (jt == 1) ? 31    : (jt == 2) ? 15    : 31;
    const int tub  = (tbj + half) >> 1; // uint base into tabh (16B-aligned)

    const int L  = cl.x;            // samples in this wave's bucket (avg 128)
    const int st = s * SPB + cl.y;

    // ---- pipeline prologue: payloads for iter0 + iter1, item rows for iter0 ----
    u64 c0 = (g < L)      ? payload[st + g]      : 0ull;
    u64 c1 = (8 + g < L)  ? payload[st + 8 + g]  : 0ull;
    u64 n0 = (16 + g < L) ? payload[st + 16 + g] : 0ull;
    u64 n1 = (24 + g < L) ? payload[st + 24 + g] : 0ull;
    {
        const int d0 = (int)((c0 >> 20) & 0x1FFFFull);
        const int d1 = (int)((c1 >> 20) & 0x1FFFFull);
        const uint4* r0 = (const uint4*)(Wh + (long)d0 * 128 + (l8 << 4));
        const uint4* r1 = (const uint4*)(Wh + (long)d1 * 128 + (l8 << 4));
        uint4 A0 = r0[0], B0 = r0[1], A1 = r1[0], B1 = r1[1];

        for (int i = 0; i < L; i += 16) {
            // (a) issue NEXT iteration's item loads (payloads n0,n1 already arrived)
            const int d0n = (int)((n0 >> 20) & 0x1FFFFull);
            const int d1n = (int)((n1 >> 20) & 0x1FFFFull);
            const uint4* r0n = (const uint4*)(Wh + (long)d0n * 128 + (l8 << 4));
            const uint4* r1n = (const uint4*)(Wh + (long)d1n * 128 + (l8 << 4));
            const uint4 A0n = r0n[0], B0n = r0n[1];
            const uint4 A1n = r1n[0], B1n = r1n[1];
            // (b) issue payloads 2 iterations ahead
            const int pi = i + 32;
            const u64 m0 = (pi + g < L)     ? payload[st + pi + g]     : 0ull;
            const u64 m1 = (pi + 8 + g < L) ? payload[st + pi + 8 + g] : 0ull;

            // (c) consume CURRENT iteration (waits only on c-loads; a/b stay in flight)
            const int ix0 = (int)((c0 >> shj) & (u64)mkj);
            const int ix1 = (int)((c1 >> shj) & (u64)mkj);
            const uint4* t0 = (const uint4*)&tabh[tub + ix0 * (NDIM / 2)];
            const uint4* t1 = (const uint4*)&tabh[tub + ix1 * (NDIM / 2)];
            const uint4 U00 = t0[0], U01 = t0[1];
            const uint4 U10 = t1[0], U11 = t1[1];

            float a0 = dot16h(A0, B0, U00, U01);
            float a1 = dot16h(A1, B1, U10, U11);

            a0 += __shfl_xor(a0, 1);  a1 += __shfl_xor(a1, 1);
            a0 += __shfl_xor(a0, 2);  a1 += __shfl_xor(a1, 2);
            a0 += __shfl_xor(a0, 4);  a1 += __shfl_xor(a1, 4);

            if (l8 == 0) {  // ids slice-local -> one 16KB out window per block
                if (i + g < L)     out[(int)(c0 & 0xFFFFFull)] = a0;
                if (i + 8 + g < L) out[(int)(c1 & 0xFFFFFull)] = a1;
            }

            // (d) rotate pipeline registers
            c0 = n0; c1 = n1; n0 = m0; n1 = m1;
            A0 = A0n; B0 = B0n; A1 = A1n; B1 = B1n;
        }
    }
}

// ---------- Pass 2 (mid): fp32 items, XCD-phased (R12 version, proven) ----------
__global__ __launch_bounds__(256, 8)
void mf_main_f32(const u64* __restrict__ payload,
                 const float* __restrict__ Wdow, const float* __restrict__ Wtim,
                 const float* __restrict__ Wmon, const float* __restrict__ Wday,
                 const float* __restrict__ Witem,
                 const int2* __restrict__ clG,
                 float* __restrict__ out)
{
    __shared__ float tab[TAB_TOT];

    const int tid = threadIdx.x;
    const int x = blockIdx.x & 7;
    const int s = blockIdx.x >> 3;

    int2 cl[4];
#pragma unroll
    for (int p = 0; p < 4; p++) cl[p] = clG[s * NB + x + 8 * p];

    load_tab(tab, Wdow, Wtim, Wmon, Wday, 256);
    __syncthreads();

    const int sub = tid & 63;
    const int wv  = tid >> 6;
    const int g   = sub >> 3;
    const int l8  = sub & 7;
    const int col = l8 * 4;
    const int tb[4] = {B_DOW, B_TIM, B_MON, B_DAY};
    const int sh[4] = {37, 40, 45, 49};
    const int mk[4] = {7, 31, 15, 31};
    for (int p = 0; p < 4; p++) {
        const int L  = cl[p].x;
        const int st = s * SPB + cl[p].y;
        for (int i = wv * 16; i < L; i += 64) {
            const int i0 = i + g, i1 = i + 8 + g;
            const bool v0 = i0 < L, v1 = i1 < L;
            const u64 p0 = v0 ? payload[st + i0] : 0ull;
            const u64 p1 = v1 ? payload[st + i1] : 0ull;
            const int d0 = (int)((p0 >> 20) & 0x1FFFFull);
            const int d1 = (int)((p1 >> 20) & 0x1FFFFull);
            const float* r0 = Witem + (long)d0 * 128 + col;
            const float* r1 = Witem + (long)d1 * 128 + col;
            float4 it0[4], it1[4], us0[4], us1[4];
#pragma unroll
            for (int j = 0; j < 4; j++) it0[j] = *reinterpret_cast<const float4*>(r0 + j * NDIM);
#pragma unroll
            for (int j = 0; j < 4; j++) it1[j] = *reinterpret_cast<const float4*>(r1 + j * NDIM);
#pragma unroll
            for (int j = 0; j < 4; j++) {
                const int idx = (int)((p0 >> sh[j]) & (u64)mk[j]);
                us0[j] = *reinterpret_cast<const float4*>(&tab[tb[j] + idx * NDIM + col]);
            }
#pragma unroll
            for (int j = 0; j < 4; j++) {
                const int idx = (int)((p1 >> sh[j]) & (u64)mk[j]);
                us1[j] = *reinterpret_cast<const float4*>(&tab[tb[j] + idx * NDIM + col]);
            }
            float a0 = 0.f, a1 = 0.f;
#pragma unroll
            for (int j = 0; j < 4; j++) {
                a0 += it0[j].x * us0[j].x + it0[j].y * us0[j].y
                    + it0[j].z * us0[j].z + it0[j].w * us0[j].w;
                a1 += it1[j].x * us1[j].x + it1[j].y * us1[j].y
                    + it1[j].z * us1[j].z + it1[j].w * us1[j].w;
            }
            a0 += __shfl_xor(a0, 1);  a1 += __shfl_xor(a1, 1);
            a0 += __shfl_xor(a0, 2);  a1 += __shfl_xor(a1, 2);
            a0 += __shfl_xor(a0, 4);  a1 += __shfl_xor(a1, 4);
            if (l8 == 0) {
                if (v0) out[(int)(p0 & 0xFFFFFull)] = a0;
                if (v1) out[(int)(p1 & 0xFFFFFull)] = a1;
            }
        }
    }
}

// ---------- Fallback: direct fp32 ----------
__global__ __launch_bounds__(256, 8)
void mf_dot_kernel(const int* __restrict__ dow, const int* __restrict__ tim,
                   const int* __restrict__ mon, const int* __restrict__ day,
                   const int* __restrict__ dest,
                   const float* __restrict__ Wdow, const float* __restrict__ Wtim,
                   const float* __restrict__ Wmon, const float* __restrict__ Wday,
                   const float* __restrict__ Witem,
                   float* __restrict__ out, int n_samples)
{
    __shared__ float tab[TAB_TOT];
    load_tab(tab, Wdow, Wtim, Wmon, Wday, 256);
    __syncthreads();
    const int tid = threadIdx.x;
    const int lane = tid & 63, sub = lane & 31, wave = tid >> 6, half = lane >> 5;
    const int t = sub >> 3, dofs = (sub & 7) * 4;
    const int* idxp  = (t == 0) ? dow   : (t == 1) ? tim   : (t == 2) ? mon   : day;
    const int  tbase = (t == 0) ? B_DOW : (t == 1) ? B_TIM : (t == 2) ? B_MON : B_DAY;
    long n = (long)blockIdx.x * 8 + wave * 2 + half;
    const long stride = (long)gridDim.x * 8;
    for (; n < n_samples; n += stride) {
        const int idx = idxp[n];
        const int ds  = dest[n];
        const float4 u  = *reinterpret_cast<const float4*>(&tab[tbase + idx * NDIM + dofs]);
        const float4 it = *reinterpret_cast<const float4*>(&Witem[(long)ds * 128 + sub * 4]);
        float r = u.x * it.x + u.y * it.y + u.z * it.z + u.w * it.w;
        r += __shfl_xor(r, 16); r += __shfl_xor(r, 8); r += __shfl_xor(r, 4);
        r += __shfl_xor(r, 2);  r += __shfl_xor(r, 1);
        if (sub == 0) out[n] = r;
    }
}

extern "C" void kernel_launch(void* const* d_in, const int* in_sizes, int n_in,
                              void* d_out, int out_size, void* d_ws, size_t ws_size,
                              hipStream_t stream)
{
    const int*   dow   = (const int*)d_in[0];
    const int*   tim   = (const int*)d_in[1];
    const int*   mon   = (const int*)d_in[2];
    const int*   day   = (const int*)d_in[3];
    const int*   dest  = (const int*)d_in[4];
    const float* Wdow  = (const float*)d_in[5];
    const float* Wtim  = (const float*)d_in[6];
    const float* Wmon  = (const float*)d_in[7];
    const float* Wday  = (const float*)d_in[8];
    const float* Witem = (const float*)d_in[9];
    float* out = (float*)d_out;

    const int n  = in_sizes[0];      // 1048576
    const int we = in_sizes[9];      // 12,800,000
    const int cap = SLICES * SPB;    // 1<<20

    const size_t off_wh       = 64 * 1024;                          // clG int2[256*32] = 64KB
    const size_t off_pay_full = (off_wh + (size_t)we * 2 + 255) & ~(size_t)255;
    const size_t need_full    = off_pay_full + (size_t)cap * 8;     // ~33.8 MB
    const size_t off_pay_mid  = 64 * 1024;
    const size_t need_mid     = off_pay_mid + (size_t)cap * 8;      // ~8.07 MB

    if ((size_t)ws_size < need_mid || n > cap) {
        hipLaunchKernelGGL(mf_dot_kernel, dim3(2048), dim3(256), 0, stream,
                           dow, tim, mon, day, dest,
                           Wdow, Wtim, Wmon, Wday, Witem, out, n);
        return;
    }

    const bool full = (size_t)ws_size >= need_full;

    int2* clG = (int2*)d_ws;
    unsigned short* Wh = full ? (unsigned short*)((char*)d_ws + off_wh) : nullptr;
    u64* payload = (u64*)((char*)d_ws + (full ? off_pay_full : off_pay_mid));

    hipLaunchKernelGGL(prep_kernel, dim3(SLICES), dim3(BIN_T), 0, stream,
                       dow, tim, mon, day, dest, clG, payload, n,
                       Witem, Wh, we);
    if (full)
        hipLaunchKernelGGL(mf_main_f16, dim3(SLICES * 8), dim3(256), 0, stream,
                           payload, Wdow, Wtim, Wmon, Wday, Wh, clG, out);
    else
        hipLaunchKernelGGL(mf_main_f32, dim3(SLICES * 8), dim3(256), 0, stream,
                           payload, Wdow, Wtim, Wmon, Wday, Witem, clG, out);
}

// Round 6
// 143.878 us; speedup vs baseline: 1.1432x; 1.0275x over previous
//
#include <hip/hip_runtime.h>

// MatrixFactorization: out[n] = dot(concat(Wdow[dow],Wtim[tim],Wmon[mon],Wday[day]), Witem[dest])
//
// Evidence ladder (bench dur): R1 direct 186 -> R5 bin32 fp32 168 -> R9 bin32 bf16 153
// -> R11 direct-out 151 -> R12 f16 dot2 + cl-hoist 147.5 -> R13 fp32 NB=64 164.5 FAILED
// -> R14 block-local bin (no phasing) 150.3 FAILED -> R15 per-wave bucket + 2-stage
// pipeline 147.8 NEUTRAL (= R12 within noise: main gather is at its latency floor;
// bucket->wave mapping and explicit pipelining don't move it).
// R16: attack prep instead. Its 105MB (20 idx + 51.2 Witem + 25.6 Wh + 8 payload) has a
// 17us streaming floor but runs ~25-30us: conversion executes SERIALLY before the three
// barrier-separated binning phases inside each block, so HBM idles during barrier bubbles.
// Split the grid within one dispatch: blocks 0..255 bin only; blocks 256..1023 (768)
// grid-stride the Witem fp32->f16 conversion. Co-resident blocks overlap conversion
// streaming with binning barriers; 768 small convert blocks (4 iters each) kill the tail.
// Binning code, payload format, and main kernel are UNTOUCHED (clean A/B vs R15).
//
// ws full (~33.8 MB): [0,64K) clG int2 | [64K) Wh f16 25.6MB | payload u64 8MB
// mid (>=8.07MB): fp32-item path.  small: direct fallback.

typedef unsigned long long u64;
typedef unsigned int uint;
typedef _Float16 half_t;
typedef half_t h2 __attribute__((ext_vector_type(2)));

#if __has_builtin(__builtin_amdgcn_fdot2)
#define HAVE_FDOT2 1
#else
#define HAVE_FDOT2 0
#endif

constexpr int NDIM = 32;
constexpr int SZ_DOW = 7 * NDIM, SZ_TIM = 24 * NDIM, SZ_MON = 12 * NDIM, SZ_DAY = 31 * NDIM;
constexpr int B_DOW = 0;
constexpr int B_TIM = B_DOW + SZ_DOW;   // 224
constexpr int B_MON = B_TIM + SZ_TIM;   // 992
constexpr int B_DAY = B_MON + SZ_MON;   // 1376
constexpr int TAB_TOT = B_DAY + SZ_DAY; // 2368 floats

constexpr int NB     = 32;       // dest buckets (dest / 3125), 0.8MB f16 rows per bucket
constexpr int DDIV   = 3125;
constexpr int SLICES = 256;      // bin slices
constexpr int SPB    = 4096;     // samples per slice
constexpr int BIN_T  = 1024;
constexpr int IPT    = SPB / BIN_T;  // 4
constexpr int NCONV  = 768;      // dedicated conversion blocks (concurrent with binning)

__device__ __forceinline__ unsigned short f2h(float f) {   // RNE fp32->fp16
    return __builtin_bit_cast(unsigned short, (half_t)f);
}

__device__ __forceinline__ uint pack2h(float a, float b) {
    return (uint)f2h(a) | ((uint)f2h(b) << 16);
}

__device__ __forceinline__ float dp2(uint a, uint b, float c) {
#if HAVE_FDOT2
    return __builtin_amdgcn_fdot2(__builtin_bit_cast(h2, a), __builtin_bit_cast(h2, b), c, false);
#else
    const h2 x = __builtin_bit_cast(h2, a), y = __builtin_bit_cast(h2, b);
    return c + (float)x.x * (float)y.x + (float)x.y * (float)y.y;
#endif
}

// 16 dims: items (a,b) vs tab (ua,ub), two chains for ILP
__device__ __forceinline__ float dot16h(uint4 a, uint4 b, uint4 ua, uint4 ub) {
    float s0 = dp2(a.x, ua.x, 0.f);
    float s1 = dp2(a.y, ua.y, 0.f);
    s0 = dp2(a.z, ua.z, s0);
    s1 = dp2(a.w, ua.w, s1);
    s0 = dp2(b.x, ub.x, s0);
    s1 = dp2(b.y, ub.y, s1);
    s0 = dp2(b.z, ub.z, s0);
    s1 = dp2(b.w, ub.w, s1);
    return s0 + s1;
}

__device__ __forceinline__ void load_tab(float* tab, const float* Wdow, const float* Wtim,
                                         const float* Wmon, const float* Wday, int nthr) {
    const int t = threadIdx.x;
    for (int i = t; i < SZ_DOW; i += nthr) tab[B_DOW + i] = Wdow[i];
    for (int i = t; i < SZ_TIM; i += nthr) tab[B_TIM + i] = Wtim[i];
    for (int i = t; i < SZ_MON; i += nthr) tab[B_MON + i] = Wmon[i];
    for (int i = t; i < SZ_DAY; i += nthr) tab[B_DAY + i] = Wday[i];
}

// pack one table's fp32 rows into f16x2 pairs in LDS
__device__ __forceinline__ void load_tabh(uint* th, const float* W, int base, int sz,
                                          int t, int nthr) {
    const float2* src = (const float2*)W;
    for (int i = t; i < (sz >> 1); i += nthr) {
        const float2 v = src[i];
        th[(base >> 1) + i] = pack2h(v.x, v.y);
    }
}

// ---------- Pass 1 (fused grid): blocks [0,SLICES) bin; blocks [SLICES,SLICES+NCONV) convert ----------
__global__ __launch_bounds__(BIN_T)
void prep_kernel(const int* __restrict__ dow, const int* __restrict__ tim,
                 const int* __restrict__ mon, const int* __restrict__ day,
                 const int* __restrict__ dest,
                 int2* __restrict__ clG,
                 u64* __restrict__ payload, int n,
                 const float* __restrict__ Witem, unsigned short* __restrict__ Wh,
                 int witem_elems)
{
    __shared__ u64 stage[SPB];              // 32 KB
    __shared__ int hist[NB], cursor[NB];

    const int t = threadIdx.x, b = blockIdx.x;

    // ---- conversion blocks: pure HBM streaming, runs concurrent with bin blocks ----
    if (b >= SLICES) {
        if (!Wh) return;
        const int nf4 = witem_elems >> 2;               // 3.2M float4
        const int stride = NCONV * BIN_T;
        const float4* src = (const float4*)Witem;
        ushort4* dst = (ushort4*)Wh;
        for (int i = (b - SLICES) * BIN_T + t; i < nf4; i += stride) {
            const float4 v = src[i];
            ushort4 o;
            o.x = f2h(v.x); o.y = f2h(v.y); o.z = f2h(v.z); o.w = f2h(v.w);
            dst[i] = o;
        }
        return;
    }

    // ---- binning blocks (identical to R15 minus the inline conversion) ----
    const int g0 = b * SPB;
    const int rem = n - g0;
    const int len = rem < SPB ? rem : SPB;

    // (1) hoist bin index loads
    int dreg[IPT], pkreg[IPT];
#pragma unroll
    for (int i = 0; i < IPT; i++) {
        const int k = i * BIN_T + t;
        if (k < len) {
            const int idx = g0 + k;
            dreg[i]  = dest[idx];
            pkreg[i] = dow[idx] | (tim[idx] << 3) | (mon[idx] << 8) | (day[idx] << 12);
        } else { dreg[i] = -1; pkreg[i] = 0; }
    }

    // (2) histogram -> wave-parallel scan -> bucket-sorted scatter
    if (t < NB) hist[t] = 0;
    __syncthreads();
#pragma unroll
    for (int i = 0; i < IPT; i++)
        if (dreg[i] >= 0) atomicAdd(&hist[dreg[i] / DDIV], 1);
    __syncthreads();
    if (t < 64) {                           // wave-parallel exclusive scan over 32 bins
        int v = (t < NB) ? hist[t] : 0;
#pragma unroll
        for (int d = 1; d < NB; d <<= 1) {
            const int nv = __shfl_up(v, d);
            if (t >= d) v += nv;
        }
        if (t < NB) {
            const int base = v - hist[t];
            cursor[t] = base;
            clG[b * NB + t] = make_int2(hist[t], base);
        }
    }
    __syncthreads();
#pragma unroll
    for (int i = 0; i < IPT; i++) {
        const int k = i * BIN_T + t;
        if (k < len) {
            const int j = atomicAdd(&cursor[dreg[i] / DDIV], 1);   // LDS atomic only
            stage[j] = (u64)(unsigned)(g0 + k)
                     | ((u64)(unsigned)dreg[i]  << 20)
                     | ((u64)(unsigned)pkreg[i] << 37);
        }
    }
    __syncthreads();
#pragma unroll
    for (int i = 0; i < IPT; i++) {
        const int k = i * BIN_T + t;
        if (k < len) payload[g0 + k] = stage[k];   // coalesced
    }
}

// ---------- Pass 2 (full): per-wave bucket, 2-stage pipelined f16 gather (R15, unchanged) ----------
__global__ __launch_bounds__(256, 6)
void mf_main_f16(const u64* __restrict__ payload,
                 const float* __restrict__ Wdow, const float* __restrict__ Wtim,
                 const float* __restrict__ Wmon, const float* __restrict__ Wday,
                 const unsigned short* __restrict__ Wh,
                 const int2* __restrict__ clG,
                 float* __restrict__ out)
{
    __shared__ uint tabh[TAB_TOT / 2];      // f16x2-packed user tables (4736 B)

    const int tid = threadIdx.x;
    const int x = blockIdx.x & 7;   // intended XCD
    const int s = blockIdx.x >> 3;  // slice 0..255
    const int wv = tid >> 6;        // wave 0..3 -> owns bucket x + 8*wv

    const int2 cl = clG[s * NB + x + 8 * wv];   // wave-uniform

    load_tabh(tabh, Wdow, B_DOW, SZ_DOW, tid, 256);
    load_tabh(tabh, Wtim, B_TIM, SZ_TIM, tid, 256);
    load_tabh(tabh, Wmon, B_MON, SZ_MON, tid, 256);
    load_tabh(tabh, Wday, B_DAY, SZ_DAY, tid, 256);
    __syncthreads();

    const int sub = tid & 63;
    const int g   = sub >> 3;       // 8-lane group 0..7
    const int l8  = sub & 7;
    const int jt   = l8 >> 1;           // table id
    const int half = (l8 & 1) * 16;     // 16-dim half within table
    const int tbj  = (jt == 0) ? B_DOW : (jt == 1) ? B_TIM : (jt == 2) ? B_MON : B_DAY;
    const int shj  = (jt == 0) ? 37    : (jt == 1) ? 40    : (jt == 2) ? 45    : 49;
    const int mkj  = (jt == 0) ? 7     : (jt == 1) ? 31    : (jt == 2) ? 15    : 31;
    const int tub  = (tbj + half) >> 1; // uint base into tabh (16B-aligned)

    const int L  = cl.x;            // samples in this wave's bucket (avg 128)
    const int st = s * SPB + cl.y;

    // ---- pipeline prologue: payloads for iter0 + iter1, item rows for iter0 ----
    u64 c0 = (g < L)      ? payload[st + g]      : 0ull;
    u64 c1 = (8 + g < L)  ? payload[st + 8 + g]  : 0ull;
    u64 n0 = (16 + g < L) ? payload[st + 16 + g] : 0ull;
    u64 n1 = (24 + g < L) ? payload[st + 24 + g] : 0ull;
    {
        const int d0 = (int)((c0 >> 20) & 0x1FFFFull);
        const int d1 = (int)((c1 >> 20) & 0x1FFFFull);
        const uint4* r0 = (const uint4*)(Wh + (long)d0 * 128 + (l8 << 4));
        const uint4* r1 = (const uint4*)(Wh + (long)d1 * 128 + (l8 << 4));
        uint4 A0 = r0[0], B0 = r0[1], A1 = r1[0], B1 = r1[1];

        for (int i = 0; i < L; i += 16) {
            // (a) issue NEXT iteration's item loads (payloads n0,n1 already arrived)
            const int d0n = (int)((n0 >> 20) & 0x1FFFFull);
            const int d1n = (int)((n1 >> 20) & 0x1FFFFull);
            const uint4* r0n = (const uint4*)(Wh + (long)d0n * 128 + (l8 << 4));
            const uint4* r1n = (const uint4*)(Wh + (long)d1n * 128 + (l8 << 4));
            const uint4 A0n = r0n[0], B0n = r0n[1];
            const uint4 A1n = r1n[0], B1n = r1n[1];
            // (b) issue payloads 2 iterations ahead
            const int pi = i + 32;
            const u64 m0 = (pi + g < L)     ? payload[st + pi + g]     : 0ull;
            const u64 m1 = (pi + 8 + g < L) ? payload[st + pi + 8 + g] : 0ull;

            // (c) consume CURRENT iteration (waits only on c-loads; a/b stay in flight)
            const int ix0 = (int)((c0 >> shj) & (u64)mkj);
            const int ix1 = (int)((c1 >> shj) & (u64)mkj);
            const uint4* t0 = (const uint4*)&tabh[tub + ix0 * (NDIM / 2)];
            const uint4* t1 = (const uint4*)&tabh[tub + ix1 * (NDIM / 2)];
            const uint4 U00 = t0[0], U01 = t0[1];
            const uint4 U10 = t1[0], U11 = t1[1];

            float a0 = dot16h(A0, B0, U00, U01);
            float a1 = dot16h(A1, B1, U10, U11);

            a0 += __shfl_xor(a0, 1);  a1 += __shfl_xor(a1, 1);
            a0 += __shfl_xor(a0, 2);  a1 += __shfl_xor(a1, 2);
            a0 += __shfl_xor(a0, 4);  a1 += __shfl_xor(a1, 4);

            if (l8 == 0) {  // ids slice-local -> one 16KB out window per block
                if (i + g < L)     out[(int)(c0 & 0xFFFFFull)] = a0;
                if (i + 8 + g < L) out[(int)(c1 & 0xFFFFFull)] = a1;
            }

            // (d) rotate pipeline registers
            c0 = n0; c1 = n1; n0 = m0; n1 = m1;
            A0 = A0n; B0 = B0n; A1 = A1n; B1 = B1n;
        }
    }
}

// ---------- Pass 2 (mid): fp32 items, XCD-phased (R12 version, proven) ----------
__global__ __launch_bounds__(256, 8)
void mf_main_f32(const u64* __restrict__ payload,
                 const float* __restrict__ Wdow, const float* __restrict__ Wtim,
                 const float* __restrict__ Wmon, const float* __restrict__ Wday,
                 const float* __restrict__ Witem,
                 const int2* __restrict__ clG,
                 float* __restrict__ out)
{
    __shared__ float tab[TAB_TOT];

    const int tid = threadIdx.x;
    const int x = blockIdx.x & 7;
    const int s = blockIdx.x >> 3;

    int2 cl[4];
#pragma unroll
    for (int p = 0; p < 4; p++) cl[p] = clG[s * NB + x + 8 * p];

    load_tab(tab, Wdow, Wtim, Wmon, Wday, 256);
    __syncthreads();

    const int sub = tid & 63;
    const int wv  = tid >> 6;
    const int g   = sub >> 3;
    const int l8  = sub & 7;
    const int col = l8 * 4;
    const int tb[4] = {B_DOW, B_TIM, B_MON, B_DAY};
    const int sh[4] = {37, 40, 45, 49};
    const int mk[4] = {7, 31, 15, 31};
    for (int p = 0; p < 4; p++) {
        const int L  = cl[p].x;
        const int st = s * SPB + cl[p].y;
        for (int i = wv * 16; i < L; i += 64) {
            const int i0 = i + g, i1 = i + 8 + g;
            const bool v0 = i0 < L, v1 = i1 < L;
            const u64 p0 = v0 ? payload[st + i0] : 0ull;
            const u64 p1 = v1 ? payload[st + i1] : 0ull;
            const int d0 = (int)((p0 >> 20) & 0x1FFFFull);
            const int d1 = (int)((p1 >> 20) & 0x1FFFFull);
            const float* r0 = Witem + (long)d0 * 128 + col;
            const float* r1 = Witem + (long)d1 * 128 + col;
            float4 it0[4], it1[4], us0[4], us1[4];
#pragma unroll
            for (int j = 0; j < 4; j++) it0[j] = *reinterpret_cast<const float4*>(r0 + j * NDIM);
#pragma unroll
            for (int j = 0; j < 4; j++) it1[j] = *reinterpret_cast<const float4*>(r1 + j * NDIM);
#pragma unroll
            for (int j = 0; j < 4; j++) {
                const int idx = (int)((p0 >> sh[j]) & (u64)mk[j]);
                us0[j] = *reinterpret_cast<const float4*>(&tab[tb[j] + idx * NDIM + col]);
            }
#pragma unroll
            for (int j = 0; j < 4; j++) {
                const int idx = (int)((p1 >> sh[j]) & (u64)mk[j]);
                us1[j] = *reinterpret_cast<const float4*>(&tab[tb[j] + idx * NDIM + col]);
            }
            float a0 = 0.f, a1 = 0.f;
#pragma unroll
            for (int j = 0; j < 4; j++) {
                a0 += it0[j].x * us0[j].x + it0[j].y * us0[j].y
                    + it0[j].z * us0[j].z + it0[j].w * us0[j].w;
                a1 += it1[j].x * us1[j].x + it1[j].y * us1[j].y
                    + it1[j].z * us1[j].z + it1[j].w * us1[j].w;
            }
            a0 += __shfl_xor(a0, 1);  a1 += __shfl_xor(a1, 1);
            a0 += __shfl_xor(a0, 2);  a1 += __shfl_xor(a1, 2);
            a0 += __shfl_xor(a0, 4);  a1 += __shfl_xor(a1, 4);
            if (l8 == 0) {
                if (v0) out[(int)(p0 & 0xFFFFFull)] = a0;
                if (v1) out[(int)(p1 & 0xFFFFFull)] = a1;
            }
        }
    }
}

// ---------- Fallback: direct fp32 ----------
__global__ __launch_bounds__(256, 8)
void mf_dot_kernel(const int* __restrict__ dow, const int* __restrict__ tim,
                   const int* __restrict__ mon, const int* __restrict__ day,
                   const int* __restrict__ dest,
                   const float* __restrict__ Wdow, const float* __restrict__ Wtim,
                   const float* __restrict__ Wmon, const float* __restrict__ Wday,
                   const float* __restrict__ Witem,
                   float* __restrict__ out, int n_samples)
{
    __shared__ float tab[TAB_TOT];
    load_tab(tab, Wdow, Wtim, Wmon, Wday, 256);
    __syncthreads();
    const int tid = threadIdx.x;
    const int lane = tid & 63, sub = lane & 31, wave = tid >> 6, half = lane >> 5;
    const int t = sub >> 3, dofs = (sub & 7) * 4;
    const int* idxp  = (t == 0) ? dow   : (t == 1) ? tim   : (t == 2) ? mon   : day;
    const int  tbase = (t == 0) ? B_DOW : (t == 1) ? B_TIM : (t == 2) ? B_MON : B_DAY;
    long n = (long)blockIdx.x * 8 + wave * 2 + half;
    const long stride = (long)gridDim.x * 8;
    for (; n < n_samples; n += stride) {
        const int idx = idxp[n];
        const int ds  = dest[n];
        const float4 u  = *reinterpret_cast<const float4*>(&tab[tbase + idx * NDIM + dofs]);
        const float4 it = *reinterpret_cast<const float4*>(&Witem[(long)ds * 128 + sub * 4]);
        float r = u.x * it.x + u.y * it.y + u.z * it.z + u.w * it.w;
        r += __shfl_xor(r, 16); r += __shfl_xor(r, 8); r += __shfl_xor(r, 4);
        r += __shfl_xor(r, 2);  r += __shfl_xor(r, 1);
        if (sub == 0) out[n] = r;
    }
}

extern "C" void kernel_launch(void* const* d_in, const int* in_sizes, int n_in,
                              void* d_out, int out_size, void* d_ws, size_t ws_size,
                              hipStream_t stream)
{
    const int*   dow   = (const int*)d_in[0];
    const int*   tim   = (const int*)d_in[1];
    const int*   mon   = (const int*)d_in[2];
    const int*   day   = (const int*)d_in[3];
    const int*   dest  = (const int*)d_in[4];
    const float* Wdow  = (const float*)d_in[5];
    const float* Wtim  = (const float*)d_in[6];
    const float* Wmon  = (const float*)d_in[7];
    const float* Wday  = (const float*)d_in[8];
    const float* Witem = (const float*)d_in[9];
    float* out = (float*)d_out;

    const int n  = in_sizes[0];      // 1048576
    const int we = in_sizes[9];      // 12,800,000
    const int cap = SLICES * SPB;    // 1<<20

    const size_t off_wh       = 64 * 1024;                          // clG int2[256*32] = 64KB
    const size_t off_pay_full = (off_wh + (size_t)we * 2 + 255) & ~(size_t)255;
    const size_t need_full    = off_pay_full + (size_t)cap * 8;     // ~33.8 MB
    const size_t off_pay_mid  = 64 * 1024;
    const size_t need_mid     = off_pay_mid + (size_t)cap * 8;      // ~8.07 MB

    if ((size_t)ws_size < need_mid || n > cap) {
        hipLaunchKernelGGL(mf_dot_kernel, dim3(2048), dim3(256), 0, stream,
                           dow, tim, mon, day, dest,
                           Wdow, Wtim, Wmon, Wday, Witem, out, n);
        return;
    }

    const bool full = (size_t)ws_size >= need_full;

    int2* clG = (int2*)d_ws;
    unsigned short* Wh = full ? (unsigned short*)((char*)d_ws + off_wh) : nullptr;
    u64* payload = (u64*)((char*)d_ws + (full ? off_pay_full : off_pay_mid));

    const int prep_blocks = SLICES + (full ? NCONV : 0);
    hipLaunchKernelGGL(prep_kernel, dim3(prep_blocks), dim3(BIN_T), 0, stream,
                       dow, tim, mon, day, dest, clG, payload, n,
                       Witem, Wh, we);
    if (full)
        hipLaunchKernelGGL(mf_main_f16, dim3(SLICES * 8), dim3(256), 0, stream,
                           payload, Wdow, Wtim, Wmon, Wday, Wh, clG, out);
    else
        hipLaunchKernelGGL(mf_main_f32, dim3(SLICES * 8), dim3(256), 0, stream,
                           payload, Wdow, Wtim, Wmon, Wday, Witem, clG, out);
}